// Round 1
// baseline (982.432 us; speedup 1.0000x reference)
//
#include <hip/hip_runtime.h>
#include <hip/hip_bf16.h>
#include <cstdint>
#include <cstddef>

#define BS 2
#define SLEN 4096
#define DIM 2048
#define INNER 1024
#define NEXP 16
#define CAP 512
#define TPE (BS*CAP)      // 1024 tokens per expert
#define NTOK (BS*SLEN)    // 8192

typedef __attribute__((ext_vector_type(4))) float f32x4;
typedef __attribute__((ext_vector_type(8))) short s16x8;

static __device__ __forceinline__ unsigned short f2bf(float f){
  unsigned u = __float_as_uint(f);
  u += 0x7FFFu + ((u >> 16) & 1u);   // RNE
  return (unsigned short)(u >> 16);
}
static __device__ __forceinline__ float sigmoidf_(float x){ return 1.0f/(1.0f+expf(-x)); }

// ---------------- cast fp32 -> bf16 (vectorized) ----------------
__global__ __launch_bounds__(256) void cast_kernel(const float* __restrict__ in,
    unsigned short* __restrict__ out, long n){
  long i = ((long)blockIdx.x*256 + threadIdx.x)*8;
  if (i >= n) return;
  f32x4 a = *reinterpret_cast<const f32x4*>(in+i);
  f32x4 b = *reinterpret_cast<const f32x4*>(in+i+4);
  s16x8 o;
  o[0]=(short)f2bf(a[0]); o[1]=(short)f2bf(a[1]); o[2]=(short)f2bf(a[2]); o[3]=(short)f2bf(a[3]);
  o[4]=(short)f2bf(b[0]); o[5]=(short)f2bf(b[1]); o[6]=(short)f2bf(b[2]); o[7]=(short)f2bf(b[3]);
  *reinterpret_cast<s16x8*>(out+i) = o;
}

// ------------- transpose + cast: in (R x C) fp32 -> out (C x R) bf16 -------------
__global__ __launch_bounds__(256) void transpose_cast_kernel(const float* __restrict__ in,
    unsigned short* __restrict__ out, int R, int C){
  __shared__ float tile[32][33];
  const size_t mat = blockIdx.z;
  const float* src = in + mat*(size_t)R*C;
  unsigned short* dst = out + mat*(size_t)R*C;
  int c0 = blockIdx.x*32, r0 = blockIdx.y*32;
  int tx = threadIdx.x, ty = threadIdx.y;
  #pragma unroll
  for (int i=0;i<32;i+=8)
    tile[ty+i][tx] = src[(size_t)(r0+ty+i)*C + (c0+tx)];
  __syncthreads();
  #pragma unroll
  for (int i=0;i<32;i+=8)
    dst[(size_t)(c0+ty+i)*R + (r0+tx)] = f2bf(tile[tx][ty+i]);
}

// ---------------- timestep part of router logits: tpart[b][e] ----------------
__global__ __launch_bounds__(256) void tpart_kernel(const float* __restrict__ timestep,
    const float* __restrict__ gate_w, float* __restrict__ tpart){
  int b = blockIdx.x >> 4, e = blockIdx.x & 15;
  float acc = 0.f;
  for (int d = threadIdx.x; d < DIM; d += 256)
    acc += timestep[b*DIM + d] * gate_w[(size_t)d*NEXP + e];
  #pragma unroll
  for (int o=32;o>0;o>>=1) acc += __shfl_down(acc, o);
  __shared__ float red[4];
  int lane = threadIdx.x & 63, wid = threadIdx.x >> 6;
  if (lane==0) red[wid] = acc;
  __syncthreads();
  if (threadIdx.x==0) tpart[blockIdx.x] = red[0]+red[1]+red[2]+red[3];
}

// ---------------- router: scores[b][e][s] = sigmoid(logit), fp32 ----------------
__global__ __launch_bounds__(256) void router_kernel(const float* __restrict__ xu,
    const float* __restrict__ gate_w, const float* __restrict__ tpart,
    float* __restrict__ scores){
  const int tok = blockIdx.x;
  const int b = tok >> 12;            // SLEN = 4096
  const int s = tok & (SLEN-1);
  const float* xr = xu + (size_t)tok*DIM;
  const int d0 = threadIdx.x * 8;
  f32x4 x0 = *reinterpret_cast<const f32x4*>(xr + d0);
  f32x4 x1 = *reinterpret_cast<const f32x4*>(xr + d0 + 4);
  float p[NEXP];
  #pragma unroll
  for (int e=0;e<NEXP;e++) p[e]=0.f;
  #pragma unroll
  for (int j=0;j<8;j++){
    float xv = (j<4) ? x0[j] : x1[j-4];
    const float* gw = gate_w + (size_t)(DIM + d0 + j)*NEXP;
    f32x4 g0 = *reinterpret_cast<const f32x4*>(gw);
    f32x4 g1 = *reinterpret_cast<const f32x4*>(gw+4);
    f32x4 g2 = *reinterpret_cast<const f32x4*>(gw+8);
    f32x4 g3 = *reinterpret_cast<const f32x4*>(gw+12);
    #pragma unroll
    for (int e=0;e<4;e++){ p[e]+=xv*g0[e]; p[4+e]+=xv*g1[e]; p[8+e]+=xv*g2[e]; p[12+e]+=xv*g3[e]; }
  }
  #pragma unroll
  for (int e=0;e<NEXP;e++){
    float v = p[e];
    #pragma unroll
    for (int o=32;o>0;o>>=1) v += __shfl_down(v, o);
    p[e] = v;
  }
  __shared__ float red[4][NEXP];
  int lane = threadIdx.x & 63, wid = threadIdx.x >> 6;
  if (lane==0){
    #pragma unroll
    for (int e=0;e<NEXP;e++) red[wid][e] = p[e];
  }
  __syncthreads();
  if (threadIdx.x < NEXP){
    int e = threadIdx.x;
    float v = red[0][e]+red[1][e]+red[2][e]+red[3][e] + tpart[b*NEXP+e];
    scores[((size_t)(b*NEXP+e))*SLEN + s] = sigmoidf_(v);
  }
}

// ---------------- top-512 per (b,e) via bitonic sort in LDS ----------------
__global__ __launch_bounds__(512) void topk_kernel(const float* __restrict__ scores,
    int* __restrict__ tok_idx, float* __restrict__ gate_raw, float* __restrict__ token_sums){
  __shared__ unsigned long long keys[SLEN];
  const int b = blockIdx.x >> 4, e = blockIdx.x & 15;
  const float* sc = scores + (size_t)blockIdx.x * SLEN;   // row (b*16+e)
  for (int i = threadIdx.x; i < SLEN; i += 512){
    unsigned bits = __float_as_uint(sc[i]);               // sigmoid outputs > 0 -> monotone bits
    keys[i] = ((unsigned long long)bits << 32) | (unsigned)(SLEN-1-i);  // tie: lower i wins
  }
  __syncthreads();
  for (int k = 2; k <= SLEN; k <<= 1){
    for (int j = k >> 1; j > 0; j >>= 1){
      for (int i = threadIdx.x; i < SLEN; i += 512){
        int ixj = i ^ j;
        if (ixj > i){
          bool up = ((i & k) == 0);
          unsigned long long a = keys[i], c = keys[ixj];
          if ((a > c) == up){ keys[i] = c; keys[ixj] = a; }
        }
      }
      __syncthreads();
    }
  }
  for (int c = threadIdx.x; c < CAP; c += 512){
    unsigned long long kk = keys[SLEN-1-c];
    int s = (SLEN-1) - (int)(kk & 0xFFFFFFFFull);
    float g = __uint_as_float((unsigned)(kk >> 32));
    int slot = (e*BS + b)*CAP + c;                         // matches ref (E, bs, cap) flat order
    tok_idx[slot]  = s;
    gate_raw[slot] = g;
    atomicAdd(&token_sums[b*SLEN + s], g);
  }
}

// ---------------- GEMM1: X(bf16) @ W[:, :2I] -> fused SwiGLU -> act bf16 ----------------
// BM=128, BN=64 act-cols (dual half accumulators), BK=32; 4 waves, wave tile 64x32x2.
template<bool GATHER, bool SILU_FIRST>
__global__ __launch_bounds__(256) void gemm1_kernel(
    const unsigned short* __restrict__ X,    // [NTOK][DIM] bf16
    const unsigned short* __restrict__ WT,   // [mats][2*INNER][DIM] bf16 (n-major, k-contig)
    const int* __restrict__ tok_idx,
    unsigned short* __restrict__ act)        // [mats*rows][INNER] bf16
{
  const int e  = blockIdx.z;
  const int n0 = blockIdx.x * 64;
  const int m0 = blockIdx.y * 128;
  const int tid = threadIdx.x;

  __shared__ short At[128][40];   // +8 bf16 pad: 16B-aligned rows, ~2-way banks
  __shared__ short Bg[64][40];
  __shared__ short Bu[64][40];

  const int arow = tid >> 2;            // 0..63
  const int k8   = (tid & 3) * 8;

  size_t asrc0, asrc1;
  if (GATHER) {
    int s0 = m0 + arow, s1 = s0 + 64;
    int b0 = s0 >> 9, b1 = s1 >> 9;
    int t0 = tok_idx[(e*BS + b0)*CAP + (s0 & (CAP-1))];
    int t1 = tok_idx[(e*BS + b1)*CAP + (s1 & (CAP-1))];
    asrc0 = ((size_t)(b0*SLEN + t0))*DIM;
    asrc1 = ((size_t)(b1*SLEN + t1))*DIM;
  } else {
    asrc0 = ((size_t)(m0 + arow))*DIM;
    asrc1 = ((size_t)(m0 + arow + 64))*DIM;
  }
  const unsigned short* a0s = X + asrc0 + k8;
  const unsigned short* a1s = X + asrc1 + k8;
  const unsigned short* WTe = WT + (size_t)e * (2*INNER) * (size_t)DIM;
  const unsigned short* bgs = WTe + ((size_t)(n0 + arow))*DIM + k8;
  const unsigned short* bus = WTe + ((size_t)(INNER + n0 + arow))*DIM + k8;

  const int wid = tid >> 6, lane = tid & 63;
  const int wr = wid >> 1, wc = wid & 1;
  const int lr = lane & 15, kg = (lane >> 4) * 8;

  f32x4 accg[4][2], accu[4][2];
  #pragma unroll
  for (int i=0;i<4;i++){
    #pragma unroll
    for (int j=0;j<2;j++){ accg[i][j] = (f32x4)0.0f; accu[i][j] = (f32x4)0.0f; }
  }

  for (int kb = 0; kb < DIM; kb += 32){
    s16x8 ra0 = *reinterpret_cast<const s16x8*>(a0s + kb);
    s16x8 ra1 = *reinterpret_cast<const s16x8*>(a1s + kb);
    s16x8 rbg = *reinterpret_cast<const s16x8*>(bgs + kb);
    s16x8 rbu = *reinterpret_cast<const s16x8*>(bus + kb);
    __syncthreads();
    *reinterpret_cast<s16x8*>(&At[arow][k8])    = ra0;
    *reinterpret_cast<s16x8*>(&At[arow+64][k8]) = ra1;
    *reinterpret_cast<s16x8*>(&Bg[arow][k8])    = rbg;
    *reinterpret_cast<s16x8*>(&Bu[arow][k8])    = rbu;
    __syncthreads();
    s16x8 af[4], gf[2], uf[2];
    #pragma unroll
    for (int mi=0;mi<4;mi++) af[mi] = *reinterpret_cast<const s16x8*>(&At[wr*64+mi*16+lr][kg]);
    #pragma unroll
    for (int ni=0;ni<2;ni++){
      gf[ni] = *reinterpret_cast<const s16x8*>(&Bg[wc*32+ni*16+lr][kg]);
      uf[ni] = *reinterpret_cast<const s16x8*>(&Bu[wc*32+ni*16+lr][kg]);
    }
    #pragma unroll
    for (int mi=0;mi<4;mi++){
      #pragma unroll
      for (int ni=0;ni<2;ni++){
        accg[mi][ni] = __builtin_amdgcn_mfma_f32_16x16x32_bf16(af[mi], gf[ni], accg[mi][ni], 0, 0, 0);
        accu[mi][ni] = __builtin_amdgcn_mfma_f32_16x16x32_bf16(af[mi], uf[ni], accu[mi][ni], 0, 0, 0);
      }
    }
  }

  const size_t rowbase = GATHER ? (size_t)e * TPE : (size_t)0;
  #pragma unroll
  for (int mi=0;mi<4;mi++){
    #pragma unroll
    for (int ni=0;ni<2;ni++){
      #pragma unroll
      for (int r=0;r<4;r++){
        float g = accg[mi][ni][r], u = accu[mi][ni][r];
        float a = SILU_FIRST ? (g*sigmoidf_(g))*u : g*(u*sigmoidf_(u));
        int row = m0 + wr*64 + mi*16 + (lane>>4)*4 + r;
        int col = n0 + wc*32 + ni*16 + lr;
        act[(rowbase + row)*(size_t)INNER + col] = f2bf(a);
      }
    }
  }
}

// ---------------- GEMM2: act(bf16) @ W2 -> out fp32 (store or scaled atomicAdd) ----------------
// BM=128, BN=128, BK=32; 4 waves, wave tile 64x64.
template<bool ROUTED>
__global__ __launch_bounds__(256) void gemm2_kernel(
    const unsigned short* __restrict__ act,  // [rows][INNER] bf16
    const unsigned short* __restrict__ W2T,  // [mats][DIM][INNER] bf16
    const int* __restrict__ tok_idx,
    const float* __restrict__ gate_raw,
    const float* __restrict__ token_sums,
    float* __restrict__ out)                 // [NTOK][DIM] fp32
{
  const int e  = blockIdx.z;
  const int n0 = blockIdx.x * 128;
  const int m0 = blockIdx.y * 128;
  const int tid = threadIdx.x;

  __shared__ short At[128][40];
  __shared__ short Bt[128][40];

  const int arow = tid >> 2;
  const int k8   = (tid & 3) * 8;

  const size_t abase = (ROUTED ? (size_t)e*TPE : (size_t)0) + m0;
  const unsigned short* a0s = act + (abase + arow)*(size_t)INNER + k8;
  const unsigned short* a1s = act + (abase + arow + 64)*(size_t)INNER + k8;
  const unsigned short* W2e = W2T + (size_t)e * DIM * INNER;
  const unsigned short* b0s = W2e + ((size_t)(n0 + arow))*INNER + k8;
  const unsigned short* b1s = W2e + ((size_t)(n0 + arow + 64))*INNER + k8;

  const int wid = tid >> 6, lane = tid & 63;
  const int wr = wid >> 1, wc = wid & 1;
  const int lr = lane & 15, kg = (lane >> 4) * 8;

  f32x4 acc[4][4];
  #pragma unroll
  for (int i=0;i<4;i++){
    #pragma unroll
    for (int j=0;j<4;j++) acc[i][j] = (f32x4)0.0f;
  }

  for (int kb = 0; kb < INNER; kb += 32){
    s16x8 ra0 = *reinterpret_cast<const s16x8*>(a0s + kb);
    s16x8 ra1 = *reinterpret_cast<const s16x8*>(a1s + kb);
    s16x8 rb0 = *reinterpret_cast<const s16x8*>(b0s + kb);
    s16x8 rb1 = *reinterpret_cast<const s16x8*>(b1s + kb);
    __syncthreads();
    *reinterpret_cast<s16x8*>(&At[arow][k8])    = ra0;
    *reinterpret_cast<s16x8*>(&At[arow+64][k8]) = ra1;
    *reinterpret_cast<s16x8*>(&Bt[arow][k8])    = rb0;
    *reinterpret_cast<s16x8*>(&Bt[arow+64][k8]) = rb1;
    __syncthreads();
    s16x8 af[4], bf_[4];
    #pragma unroll
    for (int mi=0;mi<4;mi++) af[mi]  = *reinterpret_cast<const s16x8*>(&At[wr*64+mi*16+lr][kg]);
    #pragma unroll
    for (int ni=0;ni<4;ni++) bf_[ni] = *reinterpret_cast<const s16x8*>(&Bt[wc*64+ni*16+lr][kg]);
    #pragma unroll
    for (int mi=0;mi<4;mi++){
      #pragma unroll
      for (int ni=0;ni<4;ni++)
        acc[mi][ni] = __builtin_amdgcn_mfma_f32_16x16x32_bf16(af[mi], bf_[ni], acc[mi][ni], 0, 0, 0);
    }
  }

  if (ROUTED){
    #pragma unroll
    for (int mi=0;mi<4;mi++){
      #pragma unroll
      for (int r=0;r<4;r++){
        int slot = m0 + wr*64 + mi*16 + (lane>>4)*4 + r;   // 0..1023 within expert
        int b = slot >> 9;
        int gs = (e*BS + b)*CAP + (slot & (CAP-1));
        int t = tok_idx[gs];
        size_t orow = (size_t)b*SLEN + t;
        float gn = gate_raw[gs] / (token_sums[orow] + 1e-12f);  // ROUTE_SCALE = 1
        #pragma unroll
        for (int ni=0;ni<4;ni++){
          int col = n0 + wc*64 + ni*16 + lr;
          atomicAdd(&out[orow*DIM + col], acc[mi][ni][r]*gn);
        }
      }
    }
  } else {
    #pragma unroll
    for (int mi=0;mi<4;mi++){
      #pragma unroll
      for (int r=0;r<4;r++){
        size_t row = (size_t)(m0 + wr*64 + mi*16 + (lane>>4)*4 + r);
        #pragma unroll
        for (int ni=0;ni<4;ni++){
          int col = n0 + wc*64 + ni*16 + lr;
          out[row*DIM + col] = acc[mi][ni][r];
        }
      }
    }
  }
}

extern "C" void kernel_launch(void* const* d_in, const int* in_sizes, int n_in,
                              void* d_out, int out_size, void* d_ws, size_t ws_size,
                              hipStream_t stream) {
  (void)in_sizes; (void)n_in; (void)out_size; (void)ws_size;
  const float* hidden   = (const float*)d_in[0];
  const float* xu       = (const float*)d_in[1];
  const float* timestep = (const float*)d_in[2];
  const float* gate_w   = (const float*)d_in[3];
  const float* gup      = (const float*)d_in[4];
  const float* dwn      = (const float*)d_in[5];
  const float* shin     = (const float*)d_in[6];
  const float* shout    = (const float*)d_in[7];
  float* out = (float*)d_out;

  char* base = (char*)d_ws;
  size_t off = 0;
  auto alloc = [&](size_t bytes)->char*{
    char* p = base + off; off = (off + bytes + 255) & ~(size_t)255; return p;
  };
  float* token_sums = (float*)alloc((size_t)NTOK*4);
  float* tpart      = (float*)alloc((size_t)BS*NEXP*4);
  float* scores     = (float*)alloc((size_t)BS*NEXP*SLEN*4);
  int*   tok_idx    = (int*)  alloc((size_t)NEXP*BS*CAP*4);
  float* gate_raw   = (float*)alloc((size_t)NEXP*BS*CAP*4);
  unsigned short* hid_bf = (unsigned short*)alloc((size_t)NTOK*DIM*2);
  unsigned short* gupT   = (unsigned short*)alloc((size_t)NEXP*2*INNER*DIM*2);
  unsigned short* dwnT   = (unsigned short*)alloc((size_t)NEXP*DIM*INNER*2);
  unsigned short* shinT  = (unsigned short*)alloc((size_t)2*INNER*DIM*2);
  unsigned short* shoutT = (unsigned short*)alloc((size_t)DIM*INNER*2);
  unsigned short* act_s  = (unsigned short*)alloc((size_t)NTOK*INNER*2);
  unsigned short* act_r  = (unsigned short*)alloc((size_t)NEXP*TPE*INNER*2);

  hipMemsetAsync(token_sums, 0, (size_t)NTOK*4, stream);
  cast_kernel<<<(NTOK*DIM)/2048, 256, 0, stream>>>(hidden, hid_bf, (long)NTOK*DIM);
  // weight transposes: out[n][k] = w[k][n], cast to bf16
  transpose_cast_kernel<<<dim3((2*INNER)/32, DIM/32, NEXP), dim3(32,8), 0, stream>>>(gup, gupT, DIM, 2*INNER);
  transpose_cast_kernel<<<dim3(DIM/32, INNER/32, NEXP), dim3(32,8), 0, stream>>>(dwn, dwnT, INNER, DIM);
  transpose_cast_kernel<<<dim3((2*INNER)/32, DIM/32, 1), dim3(32,8), 0, stream>>>(shin, shinT, DIM, 2*INNER);
  transpose_cast_kernel<<<dim3(DIM/32, INNER/32, 1), dim3(32,8), 0, stream>>>(shout, shoutT, INNER, DIM);

  tpart_kernel<<<BS*NEXP, 256, 0, stream>>>(timestep, gate_w, tpart);
  router_kernel<<<NTOK, 256, 0, stream>>>(xu, gate_w, tpart, scores);
  topk_kernel<<<BS*NEXP, 512, 0, stream>>>(scores, tok_idx, gate_raw, token_sums);

  // shared expert: h = x@W; act = hid * silu(gate)  (silu on SECOND half)
  gemm1_kernel<false,false><<<dim3(INNER/64, NTOK/128, 1), 256, 0, stream>>>(hid_bf, shinT, nullptr, act_s);
  // routed experts: act = silu(g) * u  (silu on FIRST half), gathered rows
  gemm1_kernel<true,true><<<dim3(INNER/64, TPE/128, NEXP), 256, 0, stream>>>(hid_bf, gupT, tok_idx, act_r);

  // shared out: plain store (initializes every element of d_out)
  gemm2_kernel<false><<<dim3(DIM/128, NTOK/128, 1), 256, 0, stream>>>(act_s, shoutT, nullptr, nullptr, nullptr, out);
  // routed out: scale by normalized gate, atomicAdd on top
  gemm2_kernel<true><<<dim3(DIM/128, TPE/128, NEXP), 256, 0, stream>>>(act_r, dwnT, tok_idx, gate_raw, token_sums, out);
}